// Round 7
// baseline (120.347 us; speedup 1.0000x reference)
//
#include <hip/hip_runtime.h>
#include <hip/hip_bf16.h>

// Problem constants
#define BB 2
#define SS 2048
#define DD 64
#define HH 8
#define HD 512            // HH*DD
#define SCALE 0.125f      // 1/sqrt(64)

typedef __bf16 bf16;
typedef __attribute__((ext_vector_type(4))) __bf16 bf16x4;
typedef __attribute__((ext_vector_type(8))) __bf16 bf16x8;
typedef __attribute__((ext_vector_type(4))) float floatx4;

#define PSLOT 2097152     // bf16 elements per partial slot = BB*HH*SS*DD (4 MiB)

__device__ __forceinline__ floatx4 mfma16(bf16x8 a, bf16x8 b, floatx4 c) {
    return __builtin_amdgcn_mfma_f32_16x16x32_bf16(a, b, c, 0, 0, 0);
}

// v_mfma_f32_16x16x16_bf16 via inline asm (ISA-documented on gfx950).
// Hazard recognizer can't see inside asm: embedded s_nop 1 guarantees the
// >=2 wait states between VALU writes of A/B and the MFMA read.
#define PV_MFMA(ACC, A, B) \
    asm("s_nop 1\n\tv_mfma_f32_16x16x16_bf16 %0, %1, %2, %0" \
        : "+v"(ACC) : "v"(A), "v"(B))

// drain MFMA pipe before VALU reads of asm-MFMA results (16 cycles)
#define MFMA_DRAIN4(A0, A1, A2, A3) \
    asm volatile("s_nop 7\n\ts_nop 7" : "+v"(A0), "+v"(A1), "+v"(A2), "+v"(A3))

// async global->LDS, 16 B/lane. LDS dest = wave-uniform base + lane*16 (HW).
#define GLL(G, L) __builtin_amdgcn_global_load_lds( \
    (const __attribute__((address_space(1))) void*)(G), \
    (__attribute__((address_space(3))) void*)(L), 16, 0, 0)

__device__ __forceinline__ bf16x8 load8(const void* base, size_t idx, int f32) {
    if (f32) {
        const float* p = (const float*)base + idx;
        const float4 a = *reinterpret_cast<const float4*>(p);
        const float4 b = *reinterpret_cast<const float4*>(p + 4);
        bf16x8 r;
        r[0] = (bf16)a.x; r[1] = (bf16)a.y; r[2] = (bf16)a.z; r[3] = (bf16)a.w;
        r[4] = (bf16)b.x; r[5] = (bf16)b.y; r[6] = (bf16)b.z; r[7] = (bf16)b.w;
        return r;
    }
    return *reinterpret_cast<const bf16x8*>((const bf16*)base + idx);
}

__device__ __forceinline__ float load1(const void* base, int idx, int f32) {
    return f32 ? ((const float*)base)[idx] : (float)((const bf16*)base)[idx];
}

// ---------------------------------------------------------------------------
// Kernel 1 (R17 core + R22 premultiplied norms): QKV proj + RoPE + norms,
// 4 s-tiles per wave. qn/kn stored PREMULTIPLIED by -cc_h =
// -gamma[h]*SCALE*log2e.
// ---------------------------------------------------------------------------
__global__ __launch_bounds__(256) void proj_rope_kernel(
    const void* __restrict__ q, const void* __restrict__ Wq,
    const void* __restrict__ Wk, const void* __restrict__ Wv,
    const void* __restrict__ gamma,
    bf16* __restrict__ qh, bf16* __restrict__ kh, bf16* __restrict__ vt,
    float* __restrict__ qn, float* __restrict__ kn,
    int* __restrict__ flagw)
{
    const int lane = threadIdx.x & 63;
    const int wid  = blockIdx.x * 4 + (threadIdx.x >> 6);
    if (wid >= 3 * BB * HH * (SS / 64)) return;       // 1536 work items
    const int l16  = lane & 15;
    const int quad = lane >> 4;

    // inline dtype detection over q's first 1024 halfwords (per-wave ballot)
    int hit = 0;
    const unsigned short* qu = (const unsigned short*)q;
#pragma unroll
    for (int i = 0; i < 16; ++i) {
        const unsigned short u = qu[lane + i * 64];
        if (((u >> 7) & 0xFF) >= 134) hit = 1;
    }
    const int f32 = (__ballot(hit) != 0ull) ? 1 : 0;
    if (wid == 0 && lane == 0) *flagw = f32;

    int id = wid;                        // ((w*BB + b)*(SS/64) + st4)*HH + h
    const int h   = id % HH; id /= HH;
    const int st4 = id % (SS / 64); id /= (SS / 64);
    const int b   = id % BB; id /= BB;
    const int w   = id;                  // 0=q, 1=k, 2=v

    const void* W = (w == 0) ? Wq : (w == 1) ? Wk : Wv;
    const size_t bh = (size_t)b * HH + h;

    // W frags once (A-operand for Q/K swapped form; B-operand for V)
    bf16x8 wb0[4], wb1[4];
#pragma unroll
    for (int t = 0; t < 4; ++t) {
        const size_t wrow = (size_t)(h * 64 + t * 16 + l16) * DD;
        wb0[t] = load8(W, wrow + quad * 8, f32);
        wb1[t] = load8(W, wrow + quad * 8 + 32, f32);
    }

    // RoPE frequency constants once per t (depend only on d)
    float frevA[4], frevB[4];
    float ncc = 0.f;
    if (w < 2) {
        ncc = -load1(gamma, h, f32) * SCALE * 1.4426950408889634f;
#pragma unroll
        for (int t = 0; t < 4; ++t) {
            const int dbase = t * 16 + quad * 4;      // even
            frevA[t] = __builtin_amdgcn_exp2f(
                -(float)dbase * (13.2877123795f / 64.0f)) * 0.15915494309f;
            frevB[t] = __builtin_amdgcn_exp2f(
                -(float)(dbase + 2) * (13.2877123795f / 64.0f)) * 0.15915494309f;
        }
    }

    for (int s4 = 0; s4 < 4; ++s4) {
        const int s0 = (st4 * 4 + s4) * 16;
        const size_t qrow = ((size_t)b * SS + s0 + l16) * DD;
        bf16x8 a0 = load8(q, qrow + quad * 8, f32);
        bf16x8 a1 = load8(q, qrow + quad * 8 + 32, f32);

        floatx4 cv[4];
#pragma unroll
        for (int t = 0; t < 4; ++t) {
            floatx4 acc = {0.f, 0.f, 0.f, 0.f};
            if (w < 2) {        // swapped: C[m=d_local][n=s_local]
                acc = mfma16(wb0[t], a0, acc);
                acc = mfma16(wb1[t], a1, acc);
            } else {            // unswapped: C[m=s_local][n=d_local]
                acc = mfma16(a0, wb0[t], acc);
                acc = mfma16(a1, wb1[t], acc);
            }
            cv[t] = acc;
        }

        if (w < 2) {
            bf16*  dst  = (w == 0) ? qh : kh;
            float* ndst = (w == 0) ? qn : kn;
            const float srowf = (float)(s0 + l16);
            float nacc = 0.f;
            bf16* drow = dst + (bh * SS + s0 + l16) * DD + quad * 4;
#pragma unroll
            for (int t = 0; t < 4; ++t) {
                float revA = srowf * frevA[t]; revA -= floorf(revA);
                float revB = srowf * frevB[t]; revB -= floorf(revB);
                const float snA = __builtin_amdgcn_sinf(revA);
                const float csA = __builtin_amdgcn_cosf(revA);
                const float snB = __builtin_amdgcn_sinf(revB);
                const float csB = __builtin_amdgcn_cosf(revB);
                const float x0 = cv[t][0], x1 = cv[t][1];
                const float x2 = cv[t][2], x3 = cv[t][3];
                const float r0 = x0 * csA - x1 * snA;
                const float r1 = x0 * snA + x1 * csA;
                const float r2 = x2 * csB - x3 * snB;
                const float r3 = x2 * snB + x3 * csB;
                nacc += r0 * r0 + r1 * r1 + r2 * r2 + r3 * r3;
                bf16x4 o; o[0]=(bf16)r0; o[1]=(bf16)r1; o[2]=(bf16)r2; o[3]=(bf16)r3;
                *reinterpret_cast<bf16x4*>(drow + t * 16) = o;
            }
            nacc += __shfl_xor(nacc, 16);
            nacc += __shfl_xor(nacc, 32);
            if (quad == 0) ndst[bh * SS + s0 + l16] = ncc * nacc;  // premult
        } else {
            // tile-major V: [bh][st][dhi=t][dlo=l16][klocal=quad*4+r]
            bf16* vrow = vt + ((size_t)bh * 128 + st4 * 4 + s4) * 1024
                       + l16 * 16 + quad * 4;
#pragma unroll
            for (int t = 0; t < 4; ++t) {
                bf16x4 pv;
#pragma unroll
                for (int r = 0; r < 4; ++r) pv[r] = (bf16)cv[t][r];
                *reinterpret_cast<bf16x4*>(vrow + t * 256) = pv;
            }
        }
    }
}

// ---------------------------------------------------------------------------
// Kernel 2 (R25 chunk body; R26: NU=4 non-uniform units + forced 4-block/CU
// residency + kn register prefetch):
// pair j/(31-j) = 66 chunks exactly, split into NU units (NU=4: 17/17/16/16).
// 1024 blocks = exactly 4 blocks/CU = 4 waves/SIMD (R22's NU=6 failed
// because ~100 VGPR caps residency at ~5 waves/SIMD; 4 fits, and
// __launch_bounds__(256,4) guarantees it). kn for chunk c+1 is loaded into
// registers during chunk c (ping-pong), removing its L2 latency from the
// per-chunk chain; vmcnt(4) semantics unchanged (queue order:
// [GLL_c, (stores), kn_next, GLL_next]).
// ---------------------------------------------------------------------------
__global__ __launch_bounds__(256, 4) void attn_kernel(
    const bf16* __restrict__ qh, const bf16* __restrict__ kh,
    const bf16* __restrict__ vt, const float* __restrict__ qn,
    const float* __restrict__ kn, const void* __restrict__ gamma,
    bf16* __restrict__ partial, const int* __restrict__ flagp,
    int NU, int pb)
{
    __shared__ __align__(16) char smem[16384];  // K: 2x4KB @0; V: 2x4KB @8192
    const int f32  = *flagp;
    const int tid  = threadIdx.x;
    const int wv   = tid >> 6;
    const int lane = tid & 63;
    const int l16  = lane & 15;
    const int quad = lane >> 4;

    // XCD-pinned: bh%8 == blockIdx%8; grid = 16 * pb blocks, pb = 16*NU
    const int xcd  = blockIdx.x & 7;
    int sblk = blockIdx.x >> 3;
    const int half = (sblk >= pb) ? 1 : 0;
    const int bh   = xcd + (half << 3);
    sblk -= half * pb;

    const int j   = sblk / NU;            // pair index 0..15
    const int u   = sblk - j * NU;        // unit within pair 0..NU-1
    const int B   = 2 * (j + 1);          // chunk count of pair member q4=j

    // non-uniform unit geometry: 66 = NU units, first `rem` have U0+1 rounds
    const int U0   = 66 / NU;
    const int rem  = 66 - U0 * NU;        // NU=4 -> U0=16, rem=2 (17,17,16,16)
    const int c0   = u * U0 + ((u < rem) ? u : rem);
    const int clen = U0 + (u < rem ? 1 : 0);
    int F = 0;                            // # units entirely inside segment A
#pragma unroll
    for (int v = 0; v < 6; ++v) {
        if (v < NU) F += (((v + 1) * U0 + (((v + 1) < rem) ? (v + 1) : rem)) <= B);
    }

    const int nA  = (c0 < B) ? (((B - c0) < clen) ? (B - c0) : clen) : 0;
    const int bB  = (c0 > B) ? (c0 - B) : 0;   // segB key-chunk base
    const int slotA = u;                  // split-K slot for q4=j rows
    const int slotB = u - F;              // split-K slot for q4=31-j rows
    const int h    = bh & 7;

    const float twocc = 2.0f * load1(gamma, h, f32) * SCALE * 1.4426950408889634f;

    // current segment state (segment A = q4 j, segment B = q4 31-j)
    int q4 = (nA > 0) ? j : (31 - j);
    int s0 = (q4 * 4 + wv) * 16;

    const bf16* qb = qh + ((size_t)bh * SS + s0 + l16) * DD;
    bf16x8 aq0 = *reinterpret_cast<const bf16x8*>(qb + quad * 8);
    bf16x8 aq1 = *reinterpret_cast<const bf16x8*>(qb + quad * 8 + 32);
    float qnc_l = qn[(size_t)bh * SS + s0 + l16];   // premultiplied by -cc

    floatx4 acc0 = {0.f,0.f,0.f,0.f}, acc1 = {0.f,0.f,0.f,0.f};
    floatx4 acc2 = {0.f,0.f,0.f,0.f}, acc3 = {0.f,0.f,0.f,0.f};

    const float* knp   = kn + (size_t)bh * SS + quad * 4;       // + key (premult)
    const char* kgbase = (const char*)(kh + (size_t)bh * SS * DD);  // + t0*128
    const char* vgbase = (const char*)(vt + (size_t)bh * 131072);   // + kt*2048

    // staging maps (loop-invariant): lane stages LDS cell jK = wv*64+lane
    const int jK   = wv * 64 + lane;
    const int keyK = jK >> 3;
    const int cK   = ((jK & 7) - keyK) & 7;
    const int goffK = keyK * 128 + cK * 16;    // swizzled K source (bytes)
    const int goffV = jK * 16;                 // V identity copy
    char* ldsK = smem + wv * 1024;             // + buf*4096
    char* ldsV = smem + 8192 + wv * 1024;      // + buf*4096

    // swizzled K frag offsets (bytes within a 4KB K buffer)
    const int kro0 = (l16 * 8 + ((quad + l16) & 7)) * 16;
    const int kro1 = (l16 * 8 + ((quad + 4 + l16) & 7)) * 16;
    const int vro  = l16 * 32 + quad * 8;      // + nb*512 (+2048 for sub1)

    // flat chunk index -> key t0
#define T0_OF(C) (((C) < nA ? (c0 + (C)) : (bB + (C) - nA)) * 32)

    // partial O store: col=query=l16, row=d_local=quad*4+r
#define STORE_O(SLOT, S0) do { \
    bf16* pbp = partial + (size_t)(SLOT) * PSLOT \
              + ((size_t)bh * SS + (S0) + l16) * DD + quad * 4; \
    bf16x4 o_; \
    o_[0]=(bf16)acc0[0]; o_[1]=(bf16)acc0[1]; o_[2]=(bf16)acc0[2]; o_[3]=(bf16)acc0[3]; \
    *reinterpret_cast<bf16x4*>(pbp +  0) = o_; \
    o_[0]=(bf16)acc1[0]; o_[1]=(bf16)acc1[1]; o_[2]=(bf16)acc1[2]; o_[3]=(bf16)acc1[3]; \
    *reinterpret_cast<bf16x4*>(pbp + 16) = o_; \
    o_[0]=(bf16)acc2[0]; o_[1]=(bf16)acc2[1]; o_[2]=(bf16)acc2[2]; o_[3]=(bf16)acc2[3]; \
    *reinterpret_cast<bf16x4*>(pbp + 32) = o_; \
    o_[0]=(bf16)acc3[0]; o_[1]=(bf16)acc3[1]; o_[2]=(bf16)acc3[2]; o_[3]=(bf16)acc3[3]; \
    *reinterpret_cast<bf16x4*>(pbp + 48) = o_; \
} while (0)

    // prologue: kn for chunk 0 into registers; stage chunk 0 into buf 0
    const int t0p = T0_OF(0);
    float4 knv0 = *reinterpret_cast<const float4*>(knp + t0p);
    float4 knv1 = *reinterpret_cast<const float4*>(knp + t0p + 16);
    GLL(kgbase + (size_t)t0p * 128 + goffK, ldsK);
    GLL(vgbase + (size_t)(t0p >> 4) * 2048 + goffV, ldsV);

    int buf = 0;
    for (int c = 0; c < clen; ++c) {
        // closes prev-iter reads of buf^1 (ds data all register-consumed
        // before this point) -> safe to overwrite buf^1 below. No vmem drain.
        __builtin_amdgcn_s_barrier();

        const int t0 = T0_OF(c);

        if (c == nA && nA > 0) {
            // pair-boundary: flush segment A, switch to q4 = 31-j
            MFMA_DRAIN4(acc0, acc1, acc2, acc3);
            STORE_O(slotA, s0);
            acc0 = {0.f,0.f,0.f,0.f}; acc1 = {0.f,0.f,0.f,0.f};
            acc2 = {0.f,0.f,0.f,0.f}; acc3 = {0.f,0.f,0.f,0.f};
            q4 = 31 - j;
            s0 = (q4 * 4 + wv) * 16;
            const bf16* qb2 = qh + ((size_t)bh * SS + s0 + l16) * DD;
            aq0 = *reinterpret_cast<const bf16x8*>(qb2 + quad * 8);
            aq1 = *reinterpret_cast<const bf16x8*>(qb2 + quad * 8 + 32);
            qnc_l = qn[(size_t)bh * SS + s0 + l16];
        }

        asm volatile("" ::: "memory");   // pin issue order: stores above, loads below

        // NEXT chunk's kn into registers + K/V prefetch into other buffer;
        // dummy re-stage on the last iter keeps queue depth uniform.
        const int tn = T0_OF((c + 1 < clen) ? (c + 1) : c);
        float4 knn0 = *reinterpret_cast<const float4*>(knp + tn);
        float4 knn1 = *reinterpret_cast<const float4*>(knp + tn + 16);
        GLL(kgbase + (size_t)tn * 128 + goffK, ldsK + ((buf ^ 1) << 12));
        GLL(vgbase + (size_t)(tn >> 4) * 2048 + goffV, ldsV + ((buf ^ 1) << 12));

        // FIFO queue: [GLL_c(2), (boundary stores), knn(2), GLL_{c+1}(2)]
        // -> vmcnt(4) drains GLL_c (+stores); knn + next prefetch stay in flight
        asm volatile("s_waitcnt vmcnt(4)" ::: "memory");

        const char* Kb = smem + (buf << 12);
        const char* Vb = smem + 8192 + (buf << 12);

        bf16x8 kc0 = *reinterpret_cast<const bf16x8*>(Kb + kro0);
        bf16x8 kc1 = *reinterpret_cast<const bf16x8*>(Kb + kro1);
        bf16x8 kc2 = *reinterpret_cast<const bf16x8*>(Kb + 2048 + kro0);
        bf16x8 kc3 = *reinterpret_cast<const bf16x8*>(Kb + 2048 + kro1);
        bf16x4 v00 = *reinterpret_cast<const bf16x4*>(Vb + vro);
        bf16x4 v01 = *reinterpret_cast<const bf16x4*>(Vb + 512 + vro);
        bf16x4 v02 = *reinterpret_cast<const bf16x4*>(Vb + 1024 + vro);
        bf16x4 v03 = *reinterpret_cast<const bf16x4*>(Vb + 1536 + vro);
        bf16x4 v10 = *reinterpret_cast<const bf16x4*>(Vb + 2048 + vro);
        bf16x4 v11 = *reinterpret_cast<const bf16x4*>(Vb + 2560 + vro);
        bf16x4 v12 = *reinterpret_cast<const bf16x4*>(Vb + 3072 + vro);
        bf16x4 v13 = *reinterpret_cast<const bf16x4*>(Vb + 3584 + vro);

        floatx4 z0 = {0.f,0.f,0.f,0.f};
        z0 = mfma16(kc0, aq0, z0);
        z0 = mfma16(kc1, aq1, z0);
        floatx4 z1 = {0.f,0.f,0.f,0.f};
        z1 = mfma16(kc2, aq0, z1);
        z1 = mfma16(kc3, aq1, z1);

        const float* k0_ = (const float*)&knv0;
        const float* k1_ = (const float*)&knv1;
        const int diag = !(t0 + 31 <= s0);
        const int dq0 = s0 + l16 - t0 - quad * 4;

        // p0 from z0, then its 4 PVs (p1's VALU overlaps the MFMA pipe)
        bf16x4 p0;
        if (!diag) {
#pragma unroll
            for (int i = 0; i < 4; ++i) {
                float rawA = fmaf(twocc, z0[i], qnc_l + k0_[i]);
                p0[i] = (bf16)__builtin_amdgcn_exp2f(rawA);
            }
        } else {
#pragma unroll
            for (int i = 0; i < 4; ++i) {
                float rawA = fmaf(twocc, z0[i], qnc_l + k0_[i]);
                float eA = __builtin_amdgcn_exp2f(rawA);
                p0[i] = (bf16)((i <= dq0) ? eA : 0.f);
            }
        }
        PV_MFMA(acc0, v00, p0);
        PV_MFMA(acc1, v01, p0);
        PV_MFMA(acc2, v02, p0);
        PV_MFMA(acc3, v03, p0);

        bf16x4 p1;
        if (!diag) {
#pragma unroll
            for (int i = 0; i < 4; ++i) {
                float rawB = fmaf(twocc, z1[i], qnc_l + k1_[i]);
                p1[i] = (bf16)__builtin_amdgcn_exp2f(rawB);
            }
        } else {
            const int dq1 = dq0 - 16;
#pragma unroll
            for (int i = 0; i < 4; ++i) {
                float rawB = fmaf(twocc, z1[i], qnc_l + k1_[i]);
                float eB = __builtin_amdgcn_exp2f(rawB);
                p1[i] = (bf16)((i <= dq1) ? eB : 0.f);
            }
        }
        PV_MFMA(acc0, v10, p1);
        PV_MFMA(acc1, v11, p1);
        PV_MFMA(acc2, v12, p1);
        PV_MFMA(acc3, v13, p1);

        knv0 = knn0; knv1 = knn1;   // ping-pong kn into place for chunk c+1
        buf ^= 1;            // no trailing barrier: top-of-loop barrier covers WAR
    }

    MFMA_DRAIN4(acc0, acc1, acc2, acc3);
    STORE_O((nA == clen) ? slotA : slotB, s0);
#undef STORE_O
#undef T0_OF
}

// ---------------------------------------------------------------------------
// Kernel 3 (R26: generic non-uniform nact): fused split-K reduce + outproj.
// ---------------------------------------------------------------------------
template <int NACT>
__device__ __forceinline__ floatx4 opj_core(const bf16* __restrict__ partial,
                                            const void* __restrict__ Wo,
                                            int b, int srow, size_t brow,
                                            int f32, int quad) {
    floatx4 acc = {0.f, 0.f, 0.f, 0.f};
#pragma unroll 4
    for (int kk = 0; kk < HD; kk += 32) {
        const int h  = kk >> 6;
        const int d0 = (kk & 63) + quad * 8;
        const bf16* ap = partial + (((size_t)(b * 8 + h)) * SS + srow) * 64 + d0;
        bf16x8 v0 = *reinterpret_cast<const bf16x8*>(ap);
        float u[8];
#pragma unroll
        for (int i = 0; i < 8; ++i) u[i] = (float)v0[i];
#pragma unroll
        for (int s = 1; s < NACT; ++s) {
            bf16x8 vs = *reinterpret_cast<const bf16x8*>(ap + (size_t)s * PSLOT);
#pragma unroll
            for (int i = 0; i < 8; ++i) u[i] += (float)vs[i];
        }
        bf16x8 a;
#pragma unroll
        for (int i = 0; i < 8; ++i) a[i] = (bf16)u[i];
        bf16x8 w = load8(Wo, brow + kk, f32);
        acc = mfma16(a, w, acc);
    }
    return acc;
}

__global__ __launch_bounds__(256) void outproj_kernel(
    const bf16* __restrict__ partial, const void* __restrict__ Wo,
    void* __restrict__ out, const int* __restrict__ flagp, int NU)
{
    const int f32  = *flagp;
    const int ct   = threadIdx.x >> 6;
    const int lane = threadIdx.x & 63;
    const int l16  = lane & 15;
    const int quad = lane >> 4;

    const int g0   = blockIdx.x * 16;          // global row (b*SS + s)
    const int b    = g0 >> 11;
    const int s0   = g0 & (SS - 1);
    const int srow = s0 + l16;
    const size_t brow = (size_t)(ct * 16 + l16) * HD + quad * 8;

    // slots holding this row's partials (non-uniform unit decomposition):
    // q4g<=15: member A of pair j=q4g, B=2(j+1): nact = #units with start < B
    // q4g>=16: member B of pair j=31-q4g: nact = NU - #units with end <= B
    const int U0  = 66 / NU;
    const int rem = 66 - U0 * NU;
    const int q4g = s0 >> 6;
    int nact = 0;
    if (q4g < 16) {
        const int Bp = 2 * (q4g + 1);
#pragma unroll
        for (int v = 0; v < 6; ++v)
            if (v < NU) nact += ((v * U0 + ((v < rem) ? v : rem)) < Bp);
    } else {
        const int Bp = 2 * (32 - q4g);
        int F = 0;
#pragma unroll
        for (int v = 0; v < 6; ++v)
            if (v < NU) F += (((v + 1) * U0 + (((v + 1) < rem) ? (v + 1) : rem)) <= Bp);
        nact = NU - F;
    }

    floatx4 acc;
    switch (nact) {
        case 1:  acc = opj_core<1>(partial, Wo, b, srow, brow, f32, quad); break;
        case 2:  acc = opj_core<2>(partial, Wo, b, srow, brow, f32, quad); break;
        case 3:  acc = opj_core<3>(partial, Wo, b, srow, brow, f32, quad); break;
        default: acc = opj_core<4>(partial, Wo, b, srow, brow, f32, quad); break;
    }

#pragma unroll
    for (int r = 0; r < 4; ++r) {
        const size_t o = (size_t)(g0 + quad * 4 + r) * DD + ct * 16 + l16;
        if (f32) ((float*)out)[o] = acc[r];
        else     ((bf16*)out)[o]  = (bf16)acc[r];
    }
}

// ---------------------------------------------------------------------------
extern "C" void kernel_launch(void* const* d_in, const int* in_sizes, int n_in,
                              void* d_out, int out_size, void* d_ws, size_t ws_size,
                              hipStream_t stream) {
    const void* q     = d_in[0];
    const void* Wq    = d_in[1];
    const void* Wk    = d_in[2];
    const void* Wv    = d_in[3];
    const void* Wo    = d_in[4];
    const void* gamma = d_in[5];

    char* ws = (char*)d_ws;
    bf16*  qh      = (bf16*)(ws);                    // 4 MiB
    bf16*  kh      = (bf16*)(ws + 4194304);          // 4 MiB
    bf16*  vt      = (bf16*)(ws + 8388608);          // 4 MiB (tile-major)
    float* qn      = (float*)(ws + 12582912);        // 128 KiB (premult -cc)
    float* kn      = (float*)(ws + 12713984);        // 128 KiB (premult -cc)
    int*   flag    = (int*)  (ws + 12845056);
    bf16*  partial = (bf16*)(ws + 13631488);         // NU x 4 MiB slots (bf16)

    // R26: NU=4 (units 17/17/16/16) -> 1024 blocks = exactly 4 blocks/CU,
    // guaranteed resident by attn's __launch_bounds__(256,4). NU=3/2
    // fallbacks for tight workspace.
    const size_t base = 13631488ull;
    int NU;
    if      (ws_size >= base + 4ull * 4194304) NU = 4;
    else if (ws_size >= base + 3ull * 4194304) NU = 3;
    else                                       NU = 2;
    const int pb = 16 * NU;          // blocks per bh (16 pairs x NU units)

    const int nproj = 3 * BB * HH * (SS / 64);       // 1536 proj work items
    proj_rope_kernel<<<dim3((nproj + 3) / 4), dim3(256), 0, stream>>>(
        q, Wq, Wk, Wv, gamma, qh, kh, vt, qn, kn, flag);
    // XCD-pinned grid: 8 xcds x 2 bh-halves x pb blocks
    attn_kernel<<<dim3(16 * pb), dim3(256), 0, stream>>>(
        qh, kh, vt, qn, kn, gamma, partial, flag, NU, pb);
    outproj_kernel<<<dim3(BB * SS / 16), dim3(256), 0, stream>>>(
        partial, Wo, d_out, flag, NU);
}

// Round 9
// 114.291 us; speedup vs baseline: 1.0530x; 1.0530x over previous
//
#include <hip/hip_runtime.h>
#include <hip/hip_bf16.h>

// Problem constants
#define BB 2
#define SS 2048
#define DD 64
#define HH 8
#define HD 512            // HH*DD
#define SCALE 0.125f      // 1/sqrt(64)

typedef __bf16 bf16;
typedef __attribute__((ext_vector_type(4))) __bf16 bf16x4;
typedef __attribute__((ext_vector_type(8))) __bf16 bf16x8;
typedef __attribute__((ext_vector_type(4))) float floatx4;

#define PSLOT 2097152     // bf16 elements per partial slot = BB*HH*SS*DD (4 MiB)

__device__ __forceinline__ floatx4 mfma16(bf16x8 a, bf16x8 b, floatx4 c) {
    return __builtin_amdgcn_mfma_f32_16x16x32_bf16(a, b, c, 0, 0, 0);
}

// v_mfma_f32_16x16x16_bf16 via inline asm (ISA-documented on gfx950).
// Hazard recognizer can't see inside asm: embedded s_nop 1 guarantees the
// >=2 wait states between VALU writes of A/B and the MFMA read.
#define PV_MFMA(ACC, A, B) \
    asm("s_nop 1\n\tv_mfma_f32_16x16x16_bf16 %0, %1, %2, %0" \
        : "+v"(ACC) : "v"(A), "v"(B))

// drain MFMA pipe before VALU reads of asm-MFMA results (16 cycles)
#define MFMA_DRAIN4(A0, A1, A2, A3) \
    asm volatile("s_nop 7\n\ts_nop 7" : "+v"(A0), "+v"(A1), "+v"(A2), "+v"(A3))

// async global->LDS, 16 B/lane. LDS dest = wave-uniform base + lane*16 (HW).
#define GLL(G, L) __builtin_amdgcn_global_load_lds( \
    (const __attribute__((address_space(1))) void*)(G), \
    (__attribute__((address_space(3))) void*)(L), 16, 0, 0)

__device__ __forceinline__ bf16x8 load8(const void* base, size_t idx, int f32) {
    if (f32) {
        const float* p = (const float*)base + idx;
        const float4 a = *reinterpret_cast<const float4*>(p);
        const float4 b = *reinterpret_cast<const float4*>(p + 4);
        bf16x8 r;
        r[0] = (bf16)a.x; r[1] = (bf16)a.y; r[2] = (bf16)a.z; r[3] = (bf16)a.w;
        r[4] = (bf16)b.x; r[5] = (bf16)b.y; r[6] = (bf16)b.z; r[7] = (bf16)b.w;
        return r;
    }
    return *reinterpret_cast<const bf16x8*>((const bf16*)base + idx);
}

__device__ __forceinline__ float load1(const void* base, int idx, int f32) {
    return f32 ? ((const float*)base)[idx] : (float)((const bf16*)base)[idx];
}

// ---------------------------------------------------------------------------
// Kernel 1 (R17 core + R22 premultiplied norms): QKV proj + RoPE + norms,
// 4 s-tiles per wave. qn/kn stored PREMULTIPLIED by -cc_h =
// -gamma[h]*SCALE*log2e.
// ---------------------------------------------------------------------------
__global__ __launch_bounds__(256) void proj_rope_kernel(
    const void* __restrict__ q, const void* __restrict__ Wq,
    const void* __restrict__ Wk, const void* __restrict__ Wv,
    const void* __restrict__ gamma,
    bf16* __restrict__ qh, bf16* __restrict__ kh, bf16* __restrict__ vt,
    float* __restrict__ qn, float* __restrict__ kn,
    int* __restrict__ flagw)
{
    const int lane = threadIdx.x & 63;
    const int wid  = blockIdx.x * 4 + (threadIdx.x >> 6);
    if (wid >= 3 * BB * HH * (SS / 64)) return;       // 1536 work items
    const int l16  = lane & 15;
    const int quad = lane >> 4;

    // inline dtype detection over q's first 1024 halfwords (per-wave ballot)
    int hit = 0;
    const unsigned short* qu = (const unsigned short*)q;
#pragma unroll
    for (int i = 0; i < 16; ++i) {
        const unsigned short u = qu[lane + i * 64];
        if (((u >> 7) & 0xFF) >= 134) hit = 1;
    }
    const int f32 = (__ballot(hit) != 0ull) ? 1 : 0;
    if (wid == 0 && lane == 0) *flagw = f32;

    int id = wid;                        // ((w*BB + b)*(SS/64) + st4)*HH + h
    const int h   = id % HH; id /= HH;
    const int st4 = id % (SS / 64); id /= (SS / 64);
    const int b   = id % BB; id /= BB;
    const int w   = id;                  // 0=q, 1=k, 2=v

    const void* W = (w == 0) ? Wq : (w == 1) ? Wk : Wv;
    const size_t bh = (size_t)b * HH + h;

    // W frags once (A-operand for Q/K swapped form; B-operand for V)
    bf16x8 wb0[4], wb1[4];
#pragma unroll
    for (int t = 0; t < 4; ++t) {
        const size_t wrow = (size_t)(h * 64 + t * 16 + l16) * DD;
        wb0[t] = load8(W, wrow + quad * 8, f32);
        wb1[t] = load8(W, wrow + quad * 8 + 32, f32);
    }

    // RoPE frequency constants once per t (depend only on d)
    float frevA[4], frevB[4];
    float ncc = 0.f;
    if (w < 2) {
        ncc = -load1(gamma, h, f32) * SCALE * 1.4426950408889634f;
#pragma unroll
        for (int t = 0; t < 4; ++t) {
            const int dbase = t * 16 + quad * 4;      // even
            frevA[t] = __builtin_amdgcn_exp2f(
                -(float)dbase * (13.2877123795f / 64.0f)) * 0.15915494309f;
            frevB[t] = __builtin_amdgcn_exp2f(
                -(float)(dbase + 2) * (13.2877123795f / 64.0f)) * 0.15915494309f;
        }
    }

    for (int s4 = 0; s4 < 4; ++s4) {
        const int s0 = (st4 * 4 + s4) * 16;
        const size_t qrow = ((size_t)b * SS + s0 + l16) * DD;
        bf16x8 a0 = load8(q, qrow + quad * 8, f32);
        bf16x8 a1 = load8(q, qrow + quad * 8 + 32, f32);

        floatx4 cv[4];
#pragma unroll
        for (int t = 0; t < 4; ++t) {
            floatx4 acc = {0.f, 0.f, 0.f, 0.f};
            if (w < 2) {        // swapped: C[m=d_local][n=s_local]
                acc = mfma16(wb0[t], a0, acc);
                acc = mfma16(wb1[t], a1, acc);
            } else {            // unswapped: C[m=s_local][n=d_local]
                acc = mfma16(a0, wb0[t], acc);
                acc = mfma16(a1, wb1[t], acc);
            }
            cv[t] = acc;
        }

        if (w < 2) {
            bf16*  dst  = (w == 0) ? qh : kh;
            float* ndst = (w == 0) ? qn : kn;
            const float srowf = (float)(s0 + l16);
            float nacc = 0.f;
            bf16* drow = dst + (bh * SS + s0 + l16) * DD + quad * 4;
#pragma unroll
            for (int t = 0; t < 4; ++t) {
                float revA = srowf * frevA[t]; revA -= floorf(revA);
                float revB = srowf * frevB[t]; revB -= floorf(revB);
                const float snA = __builtin_amdgcn_sinf(revA);
                const float csA = __builtin_amdgcn_cosf(revA);
                const float snB = __builtin_amdgcn_sinf(revB);
                const float csB = __builtin_amdgcn_cosf(revB);
                const float x0 = cv[t][0], x1 = cv[t][1];
                const float x2 = cv[t][2], x3 = cv[t][3];
                const float r0 = x0 * csA - x1 * snA;
                const float r1 = x0 * snA + x1 * csA;
                const float r2 = x2 * csB - x3 * snB;
                const float r3 = x2 * snB + x3 * csB;
                nacc += r0 * r0 + r1 * r1 + r2 * r2 + r3 * r3;
                bf16x4 o; o[0]=(bf16)r0; o[1]=(bf16)r1; o[2]=(bf16)r2; o[3]=(bf16)r3;
                *reinterpret_cast<bf16x4*>(drow + t * 16) = o;
            }
            nacc += __shfl_xor(nacc, 16);
            nacc += __shfl_xor(nacc, 32);
            if (quad == 0) ndst[bh * SS + s0 + l16] = ncc * nacc;  // premult
        } else {
            // tile-major V: [bh][st][dhi=t][dlo=l16][klocal=quad*4+r]
            bf16* vrow = vt + ((size_t)bh * 128 + st4 * 4 + s4) * 1024
                       + l16 * 16 + quad * 4;
#pragma unroll
            for (int t = 0; t < 4; ++t) {
                bf16x4 pv;
#pragma unroll
                for (int r = 0; r < 4; ++r) pv[r] = (bf16)cv[t][r];
                *reinterpret_cast<bf16x4*>(vrow + t * 256) = pv;
            }
        }
    }
}

// ---------------------------------------------------------------------------
// Kernel 2 — EXACT R25 revert (validated 114.71 us): R21 pair decomposition
// @ NU=3, R23 counted-vmcnt pipeline, R25 p0/p1-interleaved PV tail.
// R27's 64-key-round restructure FAILED correctness (absmax ~2^99 = one
// unmasked exp2 of garbage z -> bad K read from LDS). Paper-verified
// geometry; suspects: cross-wave GLL visibility race exposed by changed
// wave skew, or compiler handling of conditionally-executed "+v" asm MFMAs
// under an unrolled break. Not debuggable blind -> restore validated best.
// Wave-occupancy levers all falsified: NU=6 (R22), no-LDS regs (R24),
// forced 4/CU (R26), 64-key rounds (R19 perf / R27 correctness).
// ---------------------------------------------------------------------------
__global__ __launch_bounds__(256) void attn_kernel(
    const bf16* __restrict__ qh, const bf16* __restrict__ kh,
    const bf16* __restrict__ vt, const float* __restrict__ qn,
    const float* __restrict__ kn, const void* __restrict__ gamma,
    bf16* __restrict__ partial, const int* __restrict__ flagp,
    int NU, int U, int pb)
{
    __shared__ __align__(16) char smem[16384];  // K: 2x4KB @0; V: 2x4KB @8192
    const int f32  = *flagp;
    const int tid  = threadIdx.x;
    const int wv   = tid >> 6;
    const int lane = tid & 63;
    const int l16  = lane & 15;
    const int quad = lane >> 4;

    // XCD-pinned: bh%8 == blockIdx%8; grid = 16 * pb blocks, pb = 16*NU
    const int xcd  = blockIdx.x & 7;
    int sblk = blockIdx.x >> 3;
    const int half = (sblk >= pb) ? 1 : 0;
    const int bh   = xcd + (half << 3);
    sblk -= half * pb;

    const int j   = sblk / NU;            // pair index 0..15
    const int u   = sblk - j * NU;        // unit within pair 0..NU-1
    const int B   = 2 * (j + 1);          // chunk count of pair member q4=j
    const int c0  = u * U;                // global chunk range [c0, c0+U)
    const int nA  = (c0 < B) ? (((c0 + U) < B ? (c0 + U) : B) - c0) : 0;
    const int bB  = ((c0 > B ? c0 : B) - B);   // segB key-chunk base
    const int slotA = u;                  // split-K slot for q4=j rows
    const int slotB = u - (B / U);        // split-K slot for q4=31-j rows
    const int h    = bh & 7;

    const float twocc = 2.0f * load1(gamma, h, f32) * SCALE * 1.4426950408889634f;

    // current segment state (segment A = q4 j, segment B = q4 31-j)
    int q4 = (nA > 0) ? j : (31 - j);
    int s0 = (q4 * 4 + wv) * 16;

    const bf16* qb = qh + ((size_t)bh * SS + s0 + l16) * DD;
    bf16x8 aq0 = *reinterpret_cast<const bf16x8*>(qb + quad * 8);
    bf16x8 aq1 = *reinterpret_cast<const bf16x8*>(qb + quad * 8 + 32);
    float qnc_l = qn[(size_t)bh * SS + s0 + l16];   // premultiplied by -cc

    floatx4 acc0 = {0.f,0.f,0.f,0.f}, acc1 = {0.f,0.f,0.f,0.f};
    floatx4 acc2 = {0.f,0.f,0.f,0.f}, acc3 = {0.f,0.f,0.f,0.f};

    const float* knp   = kn + (size_t)bh * SS + quad * 4;       // + key (premult)
    const char* kgbase = (const char*)(kh + (size_t)bh * SS * DD);  // + t0*128
    const char* vgbase = (const char*)(vt + (size_t)bh * 131072);   // + kt*2048

    // staging maps (loop-invariant): lane stages LDS cell jK = wv*64+lane
    const int jK   = wv * 64 + lane;
    const int keyK = jK >> 3;
    const int cK   = ((jK & 7) - keyK) & 7;
    const int goffK = keyK * 128 + cK * 16;    // swizzled K source (bytes)
    const int goffV = jK * 16;                 // V identity copy
    char* ldsK = smem + wv * 1024;             // + buf*4096
    char* ldsV = smem + 8192 + wv * 1024;      // + buf*4096

    // swizzled K frag offsets (bytes within a 4KB K buffer)
    const int kro0 = (l16 * 8 + ((quad + l16) & 7)) * 16;
    const int kro1 = (l16 * 8 + ((quad + 4 + l16) & 7)) * 16;
    const int vro  = l16 * 32 + quad * 8;      // + nb*512 (+2048 for sub1)

    // flat chunk index -> key t0
#define T0_OF(C) (((C) < nA ? (c0 + (C)) : (bB + (C) - nA)) * 32)

    // partial O store: col=query=l16, row=d_local=quad*4+r
#define STORE_O(SLOT, S0) do { \
    bf16* pbp = partial + (size_t)(SLOT) * PSLOT \
              + ((size_t)bh * SS + (S0) + l16) * DD + quad * 4; \
    bf16x4 o_; \
    o_[0]=(bf16)acc0[0]; o_[1]=(bf16)acc0[1]; o_[2]=(bf16)acc0[2]; o_[3]=(bf16)acc0[3]; \
    *reinterpret_cast<bf16x4*>(pbp +  0) = o_; \
    o_[0]=(bf16)acc1[0]; o_[1]=(bf16)acc1[1]; o_[2]=(bf16)acc1[2]; o_[3]=(bf16)acc1[3]; \
    *reinterpret_cast<bf16x4*>(pbp + 16) = o_; \
    o_[0]=(bf16)acc2[0]; o_[1]=(bf16)acc2[1]; o_[2]=(bf16)acc2[2]; o_[3]=(bf16)acc2[3]; \
    *reinterpret_cast<bf16x4*>(pbp + 32) = o_; \
    o_[0]=(bf16)acc3[0]; o_[1]=(bf16)acc3[1]; o_[2]=(bf16)acc3[2]; o_[3]=(bf16)acc3[3]; \
    *reinterpret_cast<bf16x4*>(pbp + 48) = o_; \
} while (0)

    // prologue: stage chunk 0 into buf 0 (drained by iter-0's vmcnt(4))
    {
        const int t0p = T0_OF(0);
        GLL(kgbase + (size_t)t0p * 128 + goffK, ldsK);
        GLL(vgbase + (size_t)(t0p >> 4) * 2048 + goffV, ldsV);
    }

    int buf = 0;
    for (int c = 0; c < U; ++c) {
        // closes prev-iter reads of buf^1 (ds data all register-consumed
        // before this point) -> safe to overwrite buf^1 below. No vmem drain.
        __builtin_amdgcn_s_barrier();

        const int t0 = T0_OF(c);
        // kn loads FIRST: older than the prefetch GLLs, so their use-wait
        // is vmcnt(2) (prefetch stays in flight), not vmcnt(0).
        const float4 knv0 = *reinterpret_cast<const float4*>(knp + t0);
        const float4 knv1 = *reinterpret_cast<const float4*>(knp + t0 + 16);

        if (c == nA && nA > 0) {
            // pair-boundary: flush segment A, switch to q4 = 31-j
            MFMA_DRAIN4(acc0, acc1, acc2, acc3);
            STORE_O(slotA, s0);
            acc0 = {0.f,0.f,0.f,0.f}; acc1 = {0.f,0.f,0.f,0.f};
            acc2 = {0.f,0.f,0.f,0.f}; acc3 = {0.f,0.f,0.f,0.f};
            q4 = 31 - j;
            s0 = (q4 * 4 + wv) * 16;
            const bf16* qb2 = qh + ((size_t)bh * SS + s0 + l16) * DD;
            aq0 = *reinterpret_cast<const bf16x8*>(qb2 + quad * 8);
            aq1 = *reinterpret_cast<const bf16x8*>(qb2 + quad * 8 + 32);
            qnc_l = qn[(size_t)bh * SS + s0 + l16];
        }

        asm volatile("" ::: "memory");   // pin issue order: loads above, GLL below

        // prefetch next chunk into other buffer; dummy re-stage of the
        // current chunk on the last iter keeps queue depth uniform.
        const int tn = T0_OF((c + 1 < U) ? (c + 1) : c);
        GLL(kgbase + (size_t)tn * 128 + goffK, ldsK + ((buf ^ 1) << 12));
        GLL(vgbase + (size_t)(tn >> 4) * 2048 + goffV, ldsV + ((buf ^ 1) << 12));

        // FIFO queue here: [GLL_c(2), kn(2), GLL_{c+1}(2)] -> drain GLL_c only
        asm volatile("s_waitcnt vmcnt(4)" ::: "memory");

        const char* Kb = smem + (buf << 12);
        const char* Vb = smem + 8192 + (buf << 12);

        bf16x8 kc0 = *reinterpret_cast<const bf16x8*>(Kb + kro0);
        bf16x8 kc1 = *reinterpret_cast<const bf16x8*>(Kb + kro1);
        bf16x8 kc2 = *reinterpret_cast<const bf16x8*>(Kb + 2048 + kro0);
        bf16x8 kc3 = *reinterpret_cast<const bf16x8*>(Kb + 2048 + kro1);
        bf16x4 v00 = *reinterpret_cast<const bf16x4*>(Vb + vro);
        bf16x4 v01 = *reinterpret_cast<const bf16x4*>(Vb + 512 + vro);
        bf16x4 v02 = *reinterpret_cast<const bf16x4*>(Vb + 1024 + vro);
        bf16x4 v03 = *reinterpret_cast<const bf16x4*>(Vb + 1536 + vro);
        bf16x4 v10 = *reinterpret_cast<const bf16x4*>(Vb + 2048 + vro);
        bf16x4 v11 = *reinterpret_cast<const bf16x4*>(Vb + 2560 + vro);
        bf16x4 v12 = *reinterpret_cast<const bf16x4*>(Vb + 3072 + vro);
        bf16x4 v13 = *reinterpret_cast<const bf16x4*>(Vb + 3584 + vro);

        floatx4 z0 = {0.f,0.f,0.f,0.f};
        z0 = mfma16(kc0, aq0, z0);
        z0 = mfma16(kc1, aq1, z0);
        floatx4 z1 = {0.f,0.f,0.f,0.f};
        z1 = mfma16(kc2, aq0, z1);
        z1 = mfma16(kc3, aq1, z1);

        const float* k0_ = (const float*)&knv0;
        const float* k1_ = (const float*)&knv1;
        const int diag = !(t0 + 31 <= s0);
        const int dq0 = s0 + l16 - t0 - quad * 4;

        // p0 from z0, then its 4 PVs (p1's VALU overlaps the MFMA pipe)
        bf16x4 p0;
        if (!diag) {
#pragma unroll
            for (int i = 0; i < 4; ++i) {
                float rawA = fmaf(twocc, z0[i], qnc_l + k0_[i]);
                p0[i] = (bf16)__builtin_amdgcn_exp2f(rawA);
            }
        } else {
#pragma unroll
            for (int i = 0; i < 4; ++i) {
                float rawA = fmaf(twocc, z0[i], qnc_l + k0_[i]);
                float eA = __builtin_amdgcn_exp2f(rawA);
                p0[i] = (bf16)((i <= dq0) ? eA : 0.f);
            }
        }
        PV_MFMA(acc0, v00, p0);
        PV_MFMA(acc1, v01, p0);
        PV_MFMA(acc2, v02, p0);
        PV_MFMA(acc3, v03, p0);

        bf16x4 p1;
        if (!diag) {
#pragma unroll
            for (int i = 0; i < 4; ++i) {
                float rawB = fmaf(twocc, z1[i], qnc_l + k1_[i]);
                p1[i] = (bf16)__builtin_amdgcn_exp2f(rawB);
            }
        } else {
            const int dq1 = dq0 - 16;
#pragma unroll
            for (int i = 0; i < 4; ++i) {
                float rawB = fmaf(twocc, z1[i], qnc_l + k1_[i]);
                float eB = __builtin_amdgcn_exp2f(rawB);
                p1[i] = (bf16)((i <= dq1) ? eB : 0.f);
            }
        }
        PV_MFMA(acc0, v10, p1);
        PV_MFMA(acc1, v11, p1);
        PV_MFMA(acc2, v12, p1);
        PV_MFMA(acc3, v13, p1);

        buf ^= 1;            // no trailing barrier: top-of-loop barrier covers WAR
    }

    MFMA_DRAIN4(acc0, acc1, acc2, acc3);
    STORE_O((nA == U) ? slotA : slotB, s0);
#undef STORE_O
#undef T0_OF
}

// ---------------------------------------------------------------------------
// Kernel 3 (R21-validated): fused split-K reduce + output projection.
// ---------------------------------------------------------------------------
template <int NACT>
__device__ __forceinline__ floatx4 opj_core(const bf16* __restrict__ partial,
                                            const void* __restrict__ Wo,
                                            int b, int srow, size_t brow,
                                            int f32, int quad) {
    floatx4 acc = {0.f, 0.f, 0.f, 0.f};
#pragma unroll 4
    for (int kk = 0; kk < HD; kk += 32) {
        const int h  = kk >> 6;
        const int d0 = (kk & 63) + quad * 8;
        const bf16* ap = partial + (((size_t)(b * 8 + h)) * SS + srow) * 64 + d0;
        bf16x8 v0 = *reinterpret_cast<const bf16x8*>(ap);
        float u[8];
#pragma unroll
        for (int i = 0; i < 8; ++i) u[i] = (float)v0[i];
#pragma unroll
        for (int s = 1; s < NACT; ++s) {
            bf16x8 vs = *reinterpret_cast<const bf16x8*>(ap + (size_t)s * PSLOT);
#pragma unroll
            for (int i = 0; i < 8; ++i) u[i] += (float)vs[i];
        }
        bf16x8 a;
#pragma unroll
        for (int i = 0; i < 8; ++i) a[i] = (bf16)u[i];
        bf16x8 w = load8(Wo, brow + kk, f32);
        acc = mfma16(a, w, acc);
    }
    return acc;
}

__global__ __launch_bounds__(256) void outproj_kernel(
    const bf16* __restrict__ partial, const void* __restrict__ Wo,
    void* __restrict__ out, const int* __restrict__ flagp, int NU, int U)
{
    const int f32  = *flagp;
    const int ct   = threadIdx.x >> 6;
    const int lane = threadIdx.x & 63;
    const int l16  = lane & 15;
    const int quad = lane >> 4;

    const int g0   = blockIdx.x * 16;          // global row (b*SS + s)
    const int b    = g0 >> 11;
    const int s0   = g0 & (SS - 1);
    const int srow = s0 + l16;
    const size_t brow = (size_t)(ct * 16 + l16) * HD + quad * 8;

    // slots holding this row's partials (pair decomposition):
    // q4g<=15: member A of pair j=q4g, B=2(j+1), nact=ceil(B/U)
    // q4g>=16: member B of pair j=31-q4g, occupies [B,66), nact=NU-B/U
    const int q4g = s0 >> 6;
    int nact;
    if (q4g < 16) { const int Bp = 2 * (q4g + 1); nact = (Bp + U - 1) / U; }
    else          { const int Bp = 2 * (32 - q4g); nact = NU - Bp / U; }

    floatx4 acc;
    switch (nact) {
        case 1:  acc = opj_core<1>(partial, Wo, b, srow, brow, f32, quad); break;
        case 2:  acc = opj_core<2>(partial, Wo, b, srow, brow, f32, quad); break;
        case 3:  acc = opj_core<3>(partial, Wo, b, srow, brow, f32, quad); break;
        default: acc = opj_core<4>(partial, Wo, b, srow, brow, f32, quad); break;
    }

#pragma unroll
    for (int r = 0; r < 4; ++r) {
        const size_t o = (size_t)(g0 + quad * 4 + r) * DD + ct * 16 + l16;
        if (f32) ((float*)out)[o] = acc[r];
        else     ((bf16*)out)[o]  = (bf16)acc[r];
    }
}

// ---------------------------------------------------------------------------
extern "C" void kernel_launch(void* const* d_in, const int* in_sizes, int n_in,
                              void* d_out, int out_size, void* d_ws, size_t ws_size,
                              hipStream_t stream) {
    const void* q     = d_in[0];
    const void* Wq    = d_in[1];
    const void* Wk    = d_in[2];
    const void* Wv    = d_in[3];
    const void* Wo    = d_in[4];
    const void* gamma = d_in[5];

    char* ws = (char*)d_ws;
    bf16*  qh      = (bf16*)(ws);                    // 4 MiB
    bf16*  kh      = (bf16*)(ws + 4194304);          // 4 MiB
    bf16*  vt      = (bf16*)(ws + 8388608);          // 4 MiB (tile-major)
    float* qn      = (float*)(ws + 12582912);        // 128 KiB (premult -cc)
    float* kn      = (float*)(ws + 12713984);        // 128 KiB (premult -cc)
    int*   flag    = (int*)  (ws + 12845056);
    bf16*  partial = (bf16*)(ws + 13631488);         // NU x 4 MiB slots (bf16)

    // NU=3 (U=22) validated sweet spot (R21/R23/R25: 114.7-115.6). All
    // occupancy levers regressed or failed: NU=6 (R22), no-LDS regs (R24),
    // forced 4/CU + NU=4 (R26), 64-key rounds (R27 correctness).
    const size_t base = 13631488ull;
    int NU = (ws_size >= base + 3ull * 4194304) ? 3 : 2;
    const int U  = 66 / NU;
    const int pb = 16 * NU;          // blocks per bh (16 pairs x NU units)

    const int nproj = 3 * BB * HH * (SS / 64);       // 1536 proj work items
    proj_rope_kernel<<<dim3((nproj + 3) / 4), dim3(256), 0, stream>>>(
        q, Wq, Wk, Wv, gamma, qh, kh, vt, qn, kn, flag);
    // XCD-pinned grid: 8 xcds x 2 bh-halves x pb blocks
    attn_kernel<<<dim3(16 * pb), dim3(256), 0, stream>>>(
        qh, kh, vt, qn, kn, gamma, partial, flag, NU, U, pb);
    outproj_kernel<<<dim3(BB * SS / 16), dim3(256), 0, stream>>>(
        partial, Wo, d_out, flag, NU, U);
}